// Round 7
// baseline (4689.218 us; speedup 1.0000x reference)
//
#include <hip/hip_runtime.h>

#define V_N 20000
#define E_N 100000
#define NODE_IN_F 128
#define EDGE_IN_F 128
#define H 64
#define EDGE_HID 128
#define OUT_F 64
#define STEPS 9
#define CHUNK 5000            // nodes per N-chunk (4 chunks)

typedef __attribute__((ext_vector_type(8))) short bf16x8;
typedef __attribute__((ext_vector_type(4))) float f32x4;

__device__ __forceinline__ unsigned short f2bf(float f) {
    union { float f; unsigned int u; } v; v.f = f;
    unsigned int u = v.u;
    unsigned int r = (u + 0x7fffu + ((u >> 16) & 1u)) >> 16;  // RNE
    return (unsigned short)r;
}
__device__ __forceinline__ float bfbits(unsigned int u16) {
    union { unsigned int u; float f; } v; v.u = u16 << 16; return v.f;
}
// dot of 2 packed bf16 pairs
__device__ __forceinline__ float dot2bf(unsigned int a, unsigned int b) {
    union { unsigned int u; float f; } alo, ahi, blo, bhi;
    alo.u = a << 16; ahi.u = a & 0xffff0000u;
    blo.u = b << 16; bhi.u = b & 0xffff0000u;
    return alo.f * blo.f + ahi.f * bhi.f;
}
__device__ __forceinline__ float dot4(float4 w, float4 x) {
    return w.x * x.x + w.y * x.y + w.z * x.z + w.w * x.w;
}

// h0 = relu(nf@w1.T+b1)@w2.T+b2; zero agg & deg; hb = h0 @ b_e2; hb16/hb16lo = split(h0)
__global__ __launch_bounds__(64) void k_project(
    const float* __restrict__ nf,
    const float* __restrict__ w1, const float* __restrict__ b1,
    const float* __restrict__ w2, const float* __restrict__ b2,
    const float* __restrict__ b2e,
    float* __restrict__ h, float* __restrict__ agg, float* __restrict__ hb,
    unsigned short* __restrict__ hb16, unsigned short* __restrict__ hb16lo,
    int* __restrict__ deg)
{
    int v = blockIdx.x, t = threadIdx.x;
    __shared__ float x[NODE_IN_F], tm[H];
    const float* row = nf + (size_t)v * NODE_IN_F;
    x[t] = row[t];
    x[t + 64] = row[t + 64];
    agg[(size_t)v * H + t] = 0.f;
    if (t == 0) deg[v] = 0;
    __syncthreads();
    float acc = b1[t];
    const float4* wr = (const float4*)(w1 + (size_t)t * NODE_IN_F);
    #pragma unroll
    for (int q = 0; q < NODE_IN_F / 4; ++q) acc += dot4(wr[q], *(const float4*)&x[q * 4]);
    tm[t] = fmaxf(acc, 0.f);
    __syncthreads();
    float acc2 = b2[t];
    const float4* wr2 = (const float4*)(w2 + (size_t)t * H);
    #pragma unroll
    for (int q = 0; q < H / 4; ++q) acc2 += dot4(wr2[q], *(const float4*)&tm[q * 4]);
    h[(size_t)v * H + t] = acc2;
    unsigned short hi = f2bf(acc2);
    hb16[(size_t)v * H + t] = hi;
    hb16lo[(size_t)v * H + t] = f2bf(acc2 - bfbits(hi));
    __syncthreads();
    x[t] = acc2;
    __syncthreads();
    float acc3 = 0.f;
    for (int i = 0; i < H; ++i) acc3 += x[i] * b2e[i * 64 + t];
    hb[(size_t)v * H + t] = acc3;
}

// g = relu(ef @ w_e1.T + b_e1) -> (E,128) bf16
__global__ __launch_bounds__(256) void k_edge_g(
    const float* __restrict__ ef,
    const float* __restrict__ w1, const float* __restrict__ b1,
    unsigned short* __restrict__ g)
{
    int tid = threadIdx.x;
    int e0 = blockIdx.x * 32;
    int c = tid & 127, eg = tid >> 7;
    __shared__ float xe[32][132];
    for (int idx = tid; idx < 1024; idx += 256) {
        int e = idx >> 5, kq = idx & 31;
        float4 v = *(const float4*)(ef + (size_t)(e0 + e) * EDGE_IN_F + kq * 4);
        *(float4*)&xe[e][kq * 4] = v;
    }
    __syncthreads();
    float acc[16];
    #pragma unroll
    for (int j = 0; j < 16; ++j) acc[j] = b1[c];
    const float4* wr = (const float4*)(w1 + (size_t)c * EDGE_IN_F);
    for (int kb = 0; kb < EDGE_IN_F / 4; ++kb) {
        float4 w = wr[kb];
        #pragma unroll
        for (int j = 0; j < 16; ++j) {
            float4 x = *(const float4*)&xe[eg * 16 + j][kb * 4];
            acc[j] += dot4(w, x);
        }
    }
    #pragma unroll
    for (int j = 0; j < 16; ++j)
        g[(size_t)(e0 + eg * 16 + j) * EDGE_HID + c] = f2bf(fmaxf(acc[j], 0.f));
}

// w2rr[c][i] = bf16(w_e2[(i*64+o)*128 + k]), c = o*128+k. (8192 x 64 bf16, 1 MB)
__global__ __launch_bounds__(256) void k_w2rr(
    const float* __restrict__ w2, unsigned short* __restrict__ w2rr)
{
    int f = blockIdx.x * 256 + threadIdx.x;   // 0..524287
    int i = f & 63;
    int c = f >> 6;
    int o = c >> 7;
    int k = c & 127;
    w2rr[f] = f2bf(w2[(size_t)(i * 64 + o) * 128 + k]);
}

// CSR build (src static; rebuilt identically every call)
__global__ __launch_bounds__(256) void k_hist(const int* __restrict__ src, int* __restrict__ deg) {
    int e = blockIdx.x * 256 + threadIdx.x;
    if (e < E_N) atomicAdd(&deg[src[e]], 1);
}

__global__ __launch_bounds__(256) void k_scan(
    const int* __restrict__ deg, int* __restrict__ rowptr, int* __restrict__ cursor)
{
    const int CH = 79;   // 256*79 >= V_N
    int t = threadIdx.x;
    __shared__ int part[256];
    int base = t * CH, s = 0;
    for (int j = 0; j < CH; ++j) { int v = base + j; if (v < V_N) s += deg[v]; }
    part[t] = s;
    __syncthreads();
    if (t == 0) { int run = 0; for (int i = 0; i < 256; ++i) { int x = part[i]; part[i] = run; run += x; } }
    __syncthreads();
    int run = part[t];
    for (int j = 0; j < CH; ++j) {
        int v = base + j;
        if (v < V_N) { rowptr[v] = run; cursor[v] = run; run += deg[v]; }
    }
    if (t == 255) rowptr[V_N] = E_N;
}

__global__ __launch_bounds__(256) void k_scatter(
    const int* __restrict__ src, int* __restrict__ cursor, int* __restrict__ esort)
{
    int e = blockIdx.x * 256 + threadIdx.x;
    if (e < E_N) {
        int p = atomicAdd(&cursor[src[e]], 1);
        esort[p] = e;
    }
}

// Stage 1: N[vl][o][k] = sum_i h[v,i]*w2[(i*64+o),k]  (bf16, chunk of 5000 nodes)
// A = h split hi+lo (fp32-accurate); layouts as verified in the r3-pass k_we:
// A lane m = row m (k=q*8+j), B lane n = w2rr row c0+n over i, D col=lane&15 row=q*4+r.
__global__ __launch_bounds__(256) void k_nmat(
    const unsigned short* __restrict__ hb16, const unsigned short* __restrict__ hb16lo,
    const unsigned short* __restrict__ w2rr,
    unsigned short* __restrict__ Nc, int vbase)
{
    int tid = threadIdx.x;
    int wv = tid >> 6, lane = tid & 63;
    int m = lane & 15, q = lane >> 4;
    int vl0 = blockIdx.x * 16;
    int er = vbase + vl0 + m; if (er > V_N - 1) er = V_N - 1;
    const unsigned short* pa = hb16 + (size_t)er * 64 + q * 8;
    const unsigned short* pl = hb16lo + (size_t)er * 64 + q * 8;
    bf16x8 ah0 = *(const bf16x8*)(pa);
    bf16x8 ah1 = *(const bf16x8*)(pa + 32);
    bf16x8 al0 = *(const bf16x8*)(pl);
    bf16x8 al1 = *(const bf16x8*)(pl + 32);
    #pragma unroll 2
    for (int t_i = 0; t_i < 32; ++t_i) {
        int tile = blockIdx.y * 128 + wv * 32 + t_i;
        int c0 = tile * 16;
        const unsigned short* pb = w2rr + (size_t)(c0 + m) * 64 + q * 8;
        bf16x8 b0 = *(const bf16x8*)(pb);
        bf16x8 b1 = *(const bf16x8*)(pb + 32);
        f32x4 dacc = {0.f, 0.f, 0.f, 0.f};
        dacc = __builtin_amdgcn_mfma_f32_16x16x32_bf16(al0, b0, dacc, 0, 0, 0);
        dacc = __builtin_amdgcn_mfma_f32_16x16x32_bf16(al1, b1, dacc, 0, 0, 0);
        dacc = __builtin_amdgcn_mfma_f32_16x16x32_bf16(ah0, b0, dacc, 0, 0, 0);
        dacc = __builtin_amdgcn_mfma_f32_16x16x32_bf16(ah1, b1, dacc, 0, 0, 0);
        #pragma unroll
        for (int r = 0; r < 4; ++r) {
            int vl = vl0 + q * 4 + r;
            if (vl < CHUNK)
                Nc[(size_t)vl * 8192 + c0 + m] = f2bf(dacc[r]);
        }
    }
}

// Stage 2: per node (CSR): N[v] -> LDS (16 KB, [kc][o][8] = contiguous wave reads);
// per out-edge: msg[e,o] = sum_k g[e,k]*N[v][o,k] + hb[v,o]; atomicAdd agg[dst[e],o].
__global__ __launch_bounds__(256) void k_msg2(
    const unsigned short* __restrict__ Nc, const unsigned short* __restrict__ g,
    const float* __restrict__ hb, const int* __restrict__ rowptr,
    const int* __restrict__ esort, const int* __restrict__ dst,
    float* __restrict__ agg, int vbase)
{
    int tid = threadIdx.x;
    int wv = tid >> 6, lane = tid & 63;
    int v0 = vbase + blockIdx.x * 8;
    int vend = vbase + CHUNK;
    __shared__ unsigned short n_lds[8192];   // [kc=16][o=64][8 bf16]
    for (int s = 0; s < 8; ++s) {
        int v = v0 + s;
        if (v >= vend) break;
        int r0 = rowptr[v];
        int d = rowptr[v + 1] - r0;
        if (d == 0) continue;
        __syncthreads();
        const uint4* Ng = (const uint4*)(Nc + (size_t)(v - vbase) * 8192);
        #pragma unroll
        for (int rr = 0; rr < 4; ++rr) {
            int rdi = tid + rr * 256;          // 1024 uint4 = 16 KB
            uint4 val = Ng[rdi];
            int o = rdi >> 4, kc = rdi & 15;
            *(uint4*)&n_lds[(kc * 64 + o) * 8] = val;
        }
        __syncthreads();
        float hbv = hb[(size_t)v * 64 + lane];
        for (int j = wv; j < d; j += 4) {
            int e = esort[r0 + j];
            const uint4* ge = (const uint4*)(g + (size_t)e * 128);
            float acc = 0.f;
            #pragma unroll
            for (int kc = 0; kc < 16; ++kc) {
                uint4 gc = ge[kc];   // lane-uniform broadcast
                uint4 nc = *(const uint4*)&n_lds[(kc * 64 + lane) * 8];
                acc += dot2bf(gc.x, nc.x) + dot2bf(gc.y, nc.y)
                     + dot2bf(gc.z, nc.z) + dot2bf(gc.w, nc.w);
            }
            atomicAdd(&agg[(size_t)dst[e] * 64 + lane], acc + hbv);
        }
    }
}

// GRU; epilogue: hb = newh @ b_e2, hb16/hb16lo = split(newh); agg re-zeroed
__global__ __launch_bounds__(256) void k_gru(
    float* __restrict__ agg, const float* __restrict__ b_conv,
    const float* __restrict__ w_ih, const float* __restrict__ w_hh,
    const float* __restrict__ b_ih, const float* __restrict__ b_hh,
    const float* __restrict__ b2e,
    float* __restrict__ h, float* __restrict__ hb,
    unsigned short* __restrict__ hb16, unsigned short* __restrict__ hb16lo)
{
    int tid = threadIdx.x;
    int o = tid & 63, grp = tid >> 6;
    int vbase = blockIdx.x * 16;
    __shared__ float xl[16][68], hl[16][68];
    for (int idx = tid; idx < 16 * 64; idx += 256) {
        int n = idx >> 6, i = idx & 63;
        size_t p = (size_t)(vbase + n) * H + i;
        float a = agg[p];
        agg[p] = 0.f;
        xl[n][i] = fmaxf(a + b_conv[i], 0.f);
        hl[n][i] = h[p];
    }
    __syncthreads();
    float gir[4], giz[4], gin[4], ghr[4], ghz[4], ghn[4];
    #pragma unroll
    for (int n = 0; n < 4; ++n) {
        gir[n] = b_ih[o];       ghr[n] = b_hh[o];
        giz[n] = b_ih[64 + o];  ghz[n] = b_hh[64 + o];
        gin[n] = b_ih[128 + o]; ghn[n] = b_hh[128 + o];
    }
    const float4* wir = (const float4*)(w_ih + (size_t)o * H);
    const float4* wiz = (const float4*)(w_ih + (size_t)(64 + o) * H);
    const float4* win = (const float4*)(w_ih + (size_t)(128 + o) * H);
    const float4* whr = (const float4*)(w_hh + (size_t)o * H);
    const float4* whz = (const float4*)(w_hh + (size_t)(64 + o) * H);
    const float4* whn = (const float4*)(w_hh + (size_t)(128 + o) * H);
    #pragma unroll 4
    for (int qq = 0; qq < H / 4; ++qq) {
        float4 a1 = wir[qq], a2 = wiz[qq], a3 = win[qq];
        float4 c1 = whr[qq], c2 = whz[qq], c3 = whn[qq];
        #pragma unroll
        for (int n = 0; n < 4; ++n) {
            float4 xv = *(const float4*)&xl[grp * 4 + n][qq * 4];
            float4 hv = *(const float4*)&hl[grp * 4 + n][qq * 4];
            gir[n] += dot4(a1, xv); giz[n] += dot4(a2, xv); gin[n] += dot4(a3, xv);
            ghr[n] += dot4(c1, hv); ghz[n] += dot4(c2, hv); ghn[n] += dot4(c3, hv);
        }
    }
    float newh[4];
    #pragma unroll
    for (int n = 0; n < 4; ++n) {
        float hv = hl[grp * 4 + n][o];
        float r = 1.f / (1.f + __expf(-(gir[n] + ghr[n])));
        float z = 1.f / (1.f + __expf(-(giz[n] + ghz[n])));
        float na = gin[n] + r * ghn[n];
        float tn = 1.f - 2.f / (__expf(2.f * na) + 1.f);   // tanh
        newh[n] = (1.f - z) * tn + z * hv;
        size_t p = (size_t)(vbase + grp * 4 + n) * H + o;
        h[p] = newh[n];
        unsigned short hi = f2bf(newh[n]);
        hb16[p] = hi;
        hb16lo[p] = f2bf(newh[n] - bfbits(hi));
    }
    __syncthreads();
    #pragma unroll
    for (int n = 0; n < 4; ++n) xl[grp * 4 + n][o] = newh[n];
    __syncthreads();
    float hbacc[4] = {0.f, 0.f, 0.f, 0.f};
    for (int i = 0; i < H; ++i) {
        float w = b2e[i * 64 + o];
        #pragma unroll
        for (int n = 0; n < 4; ++n) hbacc[n] += xl[grp * 4 + n][i] * w;
    }
    #pragma unroll
    for (int n = 0; n < 4; ++n)
        hb[(size_t)(vbase + grp * 4 + n) * H + o] = hbacc[n];
}

// out = relu(h @ w_d1.T + b_d1) @ w_d2.T + b_d2  -> fp32
__global__ __launch_bounds__(64) void k_decoder(
    const float* __restrict__ h,
    const float* __restrict__ w1, const float* __restrict__ b1,
    const float* __restrict__ w2, const float* __restrict__ b2,
    float* __restrict__ out)
{
    int v = blockIdx.x, t = threadIdx.x;
    __shared__ float hl[H], tl[H];
    hl[t] = h[(size_t)v * H + t];
    __syncthreads();
    float acc = b1[t];
    const float4* wr = (const float4*)(w1 + (size_t)t * H);
    #pragma unroll
    for (int q = 0; q < H / 4; ++q) acc += dot4(wr[q], *(const float4*)&hl[q * 4]);
    tl[t] = fmaxf(acc, 0.f);
    __syncthreads();
    float acc2 = b2[t];
    const float4* wr2 = (const float4*)(w2 + (size_t)t * H);
    #pragma unroll
    for (int q = 0; q < H / 4; ++q) acc2 += dot4(wr2[q], *(const float4*)&tl[q * 4]);
    out[(size_t)v * OUT_F + t] = acc2;
}

extern "C" void kernel_launch(void* const* d_in, const int* in_sizes, int n_in,
                              void* d_out, int out_size, void* d_ws, size_t ws_size,
                              hipStream_t stream) {
    const float* nf     = (const float*)d_in[0];
    const float* ef     = (const float*)d_in[1];
    const int* src      = (const int*)d_in[2];
    const int* dst      = (const int*)d_in[3];
    const float* w_p1   = (const float*)d_in[4];
    const float* b_p1   = (const float*)d_in[5];
    const float* w_p2   = (const float*)d_in[6];
    const float* b_p2   = (const float*)d_in[7];
    const float* w_e1   = (const float*)d_in[8];
    const float* b_e1   = (const float*)d_in[9];
    const float* w_e2   = (const float*)d_in[10];
    const float* b_e2   = (const float*)d_in[11];
    const float* b_conv = (const float*)d_in[12];
    const float* w_ih   = (const float*)d_in[13];
    const float* w_hh   = (const float*)d_in[14];
    const float* b_ih   = (const float*)d_in[15];
    const float* b_hh   = (const float*)d_in[16];
    const float* w_d1   = (const float*)d_in[17];
    const float* b_d1   = (const float*)d_in[18];
    const float* w_d2   = (const float*)d_in[19];
    const float* b_d2   = (const float*)d_in[20];

    // workspace layout (~129.7 MB total, all offsets 1024-aligned)
    char* ws = (char*)d_ws;
    size_t off = 0;
    unsigned short* g      = (unsigned short*)(ws + off); off += 25600000;   // E*128 bf16
    unsigned short* w2rr   = (unsigned short*)(ws + off); off += 1048576;    // 8192*64 bf16
    float* h               = (float*)(ws + off);          off += 5120000;    // V*64 f32
    float* agg             = (float*)(ws + off);          off += 5120000;
    float* hb              = (float*)(ws + off);          off += 5120000;
    unsigned short* hb16   = (unsigned short*)(ws + off); off += 2560000;    // V*64 bf16
    unsigned short* hb16lo = (unsigned short*)(ws + off); off += 2560000;
    int* deg               = (int*)(ws + off);            off += 80896;
    int* cursor            = (int*)(ws + off);            off += 80896;
    int* rowptr            = (int*)(ws + off);            off += 80896;      // V+1 ints
    int* esort             = (int*)(ws + off);            off += 400384;     // E ints
    unsigned short* Nc     = (unsigned short*)(ws + off); off += 81920000;   // CHUNK*8192 bf16

    k_project<<<V_N, 64, 0, stream>>>(nf, w_p1, b_p1, w_p2, b_p2, b_e2,
                                      h, agg, hb, hb16, hb16lo, deg);
    k_edge_g<<<E_N / 32, 256, 0, stream>>>(ef, w_e1, b_e1, g);
    k_w2rr<<<2048, 256, 0, stream>>>(w_e2, w2rr);
    k_hist<<<(E_N + 255) / 256, 256, 0, stream>>>(src, deg);
    k_scan<<<1, 256, 0, stream>>>(deg, rowptr, cursor);
    k_scatter<<<(E_N + 255) / 256, 256, 0, stream>>>(src, cursor, esort);

    const int NT = (CHUNK + 15) / 16;          // 313 node-tiles per chunk
    const int NB2 = (CHUNK + 7) / 8;           // 625 stage-2 blocks per chunk
    for (int s = 0; s < STEPS; ++s) {
        for (int c = 0; c < 4; ++c) {
            int vbase = c * CHUNK;
            dim3 g1(NT, 4);
            k_nmat<<<g1, 256, 0, stream>>>(hb16, hb16lo, w2rr, Nc, vbase);
            k_msg2<<<NB2, 256, 0, stream>>>(Nc, g, hb, rowptr, esort, dst, agg, vbase);
        }
        k_gru<<<V_N / 16, 256, 0, stream>>>(agg, b_conv, w_ih, w_hh, b_ih, b_hh,
                                            b_e2, h, hb, hb16, hb16lo);
    }
    k_decoder<<<V_N, 64, 0, stream>>>(h, w_d1, b_d1, w_d2, b_d2, (float*)d_out);
}